// Round 1
// baseline (308.197 us; speedup 1.0000x reference)
//
#include <hip/hip_runtime.h>

#define GS 128
#define NPTS 150000
#define NBATCH 2
#define BN_TOT (NBATCH*NPTS)      // 300000
#define EPS 1e-5f

// ws layout
#define OFF_GRID   0
#define SZ_GRID    ((size_t)NBATCH*GS*GS*GS*4)       // 16,777,216 B
#define OFF_WFRAG  SZ_GRID                            // 221,184 B (27*2*4*64*8 bf16)
#define OFF_STATS  (SZ_GRID + 221184)                 // 512 B (64 sum + 64 sumsq)

typedef __attribute__((ext_vector_type(8))) short bf16x8;  // 8 bf16 in 4 VGPRs
typedef __attribute__((ext_vector_type(4))) float f32x4;

__device__ __forceinline__ short f2bf(float f) {
    union { float f; unsigned u; } v; v.f = f;
    unsigned r = v.u + 0x7fffu + ((v.u >> 16) & 1u);   // RNE, finite inputs only
    return (short)(r >> 16);
}

// ---------- kernel 1: scatter max pid into dense grid ----------
__global__ __launch_bounds__(256) void k_scatter(const int* __restrict__ coords,
                                                 int* __restrict__ grid) {
    int p = blockIdx.x * 256 + threadIdx.x;
    if (p >= BN_TOT) return;
    int b = p / NPTS;
    int x = coords[p*3+0], y = coords[p*3+1], z = coords[p*3+2];
    atomicMax(&grid[((b*GS + x)*GS + y)*GS + z], p);
}

// ---------- kernel 2: weight -> bf16 MFMA B-fragments ----------
// wfrag element t = ((((k*2+c)*4 + tt)*64 + lane)*8 + i)
//   holds W[k][ c*32 + (lane>>4)*8 + i ][ tt*16 + (lane&15) ]
__global__ __launch_bounds__(256) void k_prefrag(const float* __restrict__ w,
                                                 short* __restrict__ wfrag) {
    int t = blockIdx.x * 256 + threadIdx.x;
    if (t >= 27*2*4*64*8) return;
    int i    = t & 7;
    int lane = (t >> 3) & 63;
    int tt   = (t >> 9) & 3;
    int c    = (t >> 11) & 1;
    int k    = t >> 12;
    int kk = c*32 + (lane >> 4)*8 + i;
    int co = tt*16 + (lane & 15);
    wfrag[t] = f2bf(w[(k*64 + kk)*64 + co]);
}

// ---------- kernel 3: gathered MFMA conv ----------
// 1 wave = 16 points x 64 cout. Wave-private LDS A-tile [16][72] shorts
// (row stride 144B: 2-way banks max on both write and read sides).
__global__ __launch_bounds__(256) void k_conv(const float* __restrict__ feats,
                                              const int* __restrict__ coords,
                                              const int* __restrict__ grid,
                                              const short* __restrict__ wfrag,
                                              float* __restrict__ out) {
    const int lane = threadIdx.x & 63;
    const int wv   = threadIdx.x >> 6;
    const int wgid = blockIdx.x * 4 + wv;
    if (wgid >= BN_TOT/16) return;        // whole-wave exit; no block barriers used
    const int p0 = wgid * 16;

    __shared__ __align__(16) short lds[4][16*72];
    short* atile = lds[wv];

    const int r   = lane & 15;            // row this lane stages / A-frag row
    const int seg = lane >> 4;            // 16-elem staging segment / A k-group
    const int p   = p0 + r;
    const int pb  = p / NPTS;
    const int cx = coords[p*3+0], cy = coords[p*3+1], cz = coords[p*3+2];
    const int* gbase = grid + pb * (GS*GS*GS);

    f32x4 acc0 = {0,0,0,0}, acc1 = {0,0,0,0}, acc2 = {0,0,0,0}, acc3 = {0,0,0,0};

    auto lookup = [&](int k) -> int {
        int dx = k/9 - 1, dy = (k/3)%3 - 1, dz = k%3 - 1;
        int nx = cx+dx, ny = cy+dy, nz = cz+dz;
        if (((unsigned)nx < (unsigned)GS) & ((unsigned)ny < (unsigned)GS) &
            ((unsigned)nz < (unsigned)GS))
            return gbase[(nx*GS + ny)*GS + nz];
        return -1;
    };

    int id_next = lookup(0);
    for (int k = 0; k < 27; ++k) {
        const int id = id_next;
        if (k < 26) id_next = lookup(k+1);     // depth-1 prefetch of grid lookup
        const bool valid = (id >= 0);
        if (!__any(valid)) continue;           // wave-uniform skip

        // stage row r, cols [16*seg, 16*seg+16) as bf16 (zeros if invalid)
        float4 f0 = {0,0,0,0}, f1 = {0,0,0,0}, f2 = {0,0,0,0}, f3 = {0,0,0,0};
        if (valid) {
            const float4* src = (const float4*)(feats + (size_t)id*64 + seg*16);
            f0 = src[0]; f1 = src[1]; f2 = src[2]; f3 = src[3];
        }
        bf16x8 w0 = { f2bf(f0.x), f2bf(f0.y), f2bf(f0.z), f2bf(f0.w),
                      f2bf(f1.x), f2bf(f1.y), f2bf(f1.z), f2bf(f1.w) };
        bf16x8 w1 = { f2bf(f2.x), f2bf(f2.y), f2bf(f2.z), f2bf(f2.w),
                      f2bf(f3.x), f2bf(f3.y), f2bf(f3.z), f2bf(f3.w) };
        *(bf16x8*)(atile + r*72 + seg*16)     = w0;
        *(bf16x8*)(atile + r*72 + seg*16 + 8) = w1;

        asm volatile("s_waitcnt lgkmcnt(0)" ::: "memory");   // wave-private tile:
        __builtin_amdgcn_sched_barrier(0);                   // pin write->read order

        // A-frags: lane -> row = lane&15, k = c*32 + (lane>>4)*8 + i
        bf16x8 a0 = *(const bf16x8*)(atile + r*72 +      seg*8);
        bf16x8 a1 = *(const bf16x8*)(atile + r*72 + 32 + seg*8);

        const bf16x8* wfp = (const bf16x8*)wfrag;
        const int fb = k*8*64;                // fragidx*(64 lanes)
        bf16x8 b00 = wfp[fb + 0*64 + lane];
        bf16x8 b01 = wfp[fb + 1*64 + lane];
        bf16x8 b02 = wfp[fb + 2*64 + lane];
        bf16x8 b03 = wfp[fb + 3*64 + lane];
        bf16x8 b10 = wfp[fb + 4*64 + lane];
        bf16x8 b11 = wfp[fb + 5*64 + lane];
        bf16x8 b12 = wfp[fb + 6*64 + lane];
        bf16x8 b13 = wfp[fb + 7*64 + lane];

        acc0 = __builtin_amdgcn_mfma_f32_16x16x32_bf16(a0, b00, acc0, 0, 0, 0);
        acc1 = __builtin_amdgcn_mfma_f32_16x16x32_bf16(a0, b01, acc1, 0, 0, 0);
        acc2 = __builtin_amdgcn_mfma_f32_16x16x32_bf16(a0, b02, acc2, 0, 0, 0);
        acc3 = __builtin_amdgcn_mfma_f32_16x16x32_bf16(a0, b03, acc3, 0, 0, 0);
        acc0 = __builtin_amdgcn_mfma_f32_16x16x32_bf16(a1, b10, acc0, 0, 0, 0);
        acc1 = __builtin_amdgcn_mfma_f32_16x16x32_bf16(a1, b11, acc1, 0, 0, 0);
        acc2 = __builtin_amdgcn_mfma_f32_16x16x32_bf16(a1, b12, acc2, 0, 0, 0);
        acc3 = __builtin_amdgcn_mfma_f32_16x16x32_bf16(a1, b13, acc3, 0, 0, 0);
        __builtin_amdgcn_sched_barrier(0);    // keep ds_reads of this iter before next writes
    }

    // C/D layout (verified m89/m91): col = lane&15, row = (lane>>4)*4 + j
    const int orow = seg * 4;
    float* obase = out + (size_t)p0 * 64;
    #pragma unroll
    for (int j = 0; j < 4; ++j) {
        obase[(orow + j)*64 +  0 + r] = acc0[j];
        obase[(orow + j)*64 + 16 + r] = acc1[j];
        obase[(orow + j)*64 + 32 + r] = acc2[j];
        obase[(orow + j)*64 + 48 + r] = acc3[j];
    }
}

// ---------- kernel 4: per-channel sum / sumsq over all BN rows ----------
__global__ __launch_bounds__(256) void k_stats(const float* __restrict__ out,
                                               float* __restrict__ stats) {
    __shared__ float ss[64], sq[64];
    int t = threadIdx.x;
    if (t < 64) { ss[t] = 0.f; sq[t] = 0.f; }
    __syncthreads();
    float s0=0,s1=0,s2=0,s3=0,q0=0,q1=0,q2=0,q3=0;
    const float4* o4 = (const float4*)out;
    const int n4 = BN_TOT*16;
    for (int i = blockIdx.x*256 + t; i < n4; i += gridDim.x*256) {
        float4 v = o4[i];
        s0 += v.x; q0 += v.x*v.x;
        s1 += v.y; q1 += v.y*v.y;
        s2 += v.z; q2 += v.z*v.z;
        s3 += v.w; q3 += v.w*v.w;
    }
    int ch = (t & 15) * 4;   // stride 256*4 floats == 0 mod 64 -> fixed channels
    atomicAdd(&ss[ch+0], s0); atomicAdd(&sq[ch+0], q0);
    atomicAdd(&ss[ch+1], s1); atomicAdd(&sq[ch+1], q1);
    atomicAdd(&ss[ch+2], s2); atomicAdd(&sq[ch+2], q2);
    atomicAdd(&ss[ch+3], s3); atomicAdd(&sq[ch+3], q3);
    __syncthreads();
    if (t < 64) { atomicAdd(&stats[t], ss[t]); atomicAdd(&stats[64+t], sq[t]); }
}

// ---------- kernel 5: normalize + affine + ReLU, in place ----------
__global__ __launch_bounds__(256) void k_norm(float* __restrict__ out,
                                              const float* __restrict__ stats,
                                              const float* __restrict__ gamma,
                                              const float* __restrict__ beta) {
    int i = blockIdx.x*256 + threadIdx.x;
    const int n4 = BN_TOT*16;
    if (i >= n4) return;
    float4 v = ((const float4*)out)[i];
    int ch = (i & 15) * 4;
    float o[4] = {v.x, v.y, v.z, v.w};
    float rp[4];
    #pragma unroll
    for (int j = 0; j < 4; ++j) {
        int c = ch + j;
        float mean = stats[c] * (1.f/BN_TOT);
        float var  = stats[64+c] * (1.f/BN_TOT) - mean*mean;
        float y = (o[j] - mean) * rsqrtf(var + EPS) * gamma[c] + beta[c];
        rp[j] = fmaxf(y, 0.f);
    }
    float4 rv; rv.x = rp[0]; rv.y = rp[1]; rv.z = rp[2]; rv.w = rp[3];
    ((float4*)out)[i] = rv;
}

extern "C" void kernel_launch(void* const* d_in, const int* in_sizes, int n_in,
                              void* d_out, int out_size, void* d_ws, size_t ws_size,
                              hipStream_t stream) {
    const float* feats  = (const float*)d_in[0];
    const int*   coords = (const int*)d_in[1];
    const float* weight = (const float*)d_in[2];
    const float* gamma  = (const float*)d_in[3];
    const float* beta   = (const float*)d_in[4];
    float* out = (float*)d_out;

    char*  ws    = (char*)d_ws;
    int*   grid  = (int*)(ws + OFF_GRID);
    short* wfrag = (short*)(ws + OFF_WFRAG);
    float* stats = (float*)(ws + OFF_STATS);

    hipMemsetAsync(grid, 0xFF, SZ_GRID, stream);           // all cells = -1
    hipMemsetAsync(stats, 0, 512, stream);

    k_scatter<<<(BN_TOT + 255)/256, 256, 0, stream>>>(coords, grid);
    k_prefrag<<<(27*2*4*64*8)/256, 256, 0, stream>>>(weight, wfrag);
    k_conv<<<(BN_TOT/16 + 3)/4, 256, 0, stream>>>(feats, coords, grid, wfrag, out);
    k_stats<<<2048, 256, 0, stream>>>(out, stats);
    k_norm<<<(BN_TOT*16 + 255)/256, 256, 0, stream>>>(out, stats, gamma, beta);
}

// Round 2
// 219.246 us; speedup vs baseline: 1.4057x; 1.4057x over previous
//
#include <hip/hip_runtime.h>

#define GS 128
#define GS3 (GS*GS*GS)
#define NPTS 150000
#define NBATCH 2
#define BN_TOT (NBATCH*NPTS)      // 300000
#define EPS 1e-5f

#define CONV_BLOCKS 1172          // ceil(300000 / 256), pad rows masked

// ws layout
#define OFF_GRID   0ull
#define SZ_GRID    ((size_t)NBATCH*GS3*4)             // 16,777,216 B
#define OFF_WFRAG  SZ_GRID                             // 27*8*64*8 bf16 = 221,184 B
#define SZ_WFRAG   ((size_t)27*8*64*8*2)
#define OFF_STATS  (OFF_WFRAG + SZ_WFRAG)              // 512 B
#define OFF_FB16   (OFF_STATS + 512)                   // 300000*64 bf16 = 38,400,000 B
#define SZ_FB16    ((size_t)BN_TOT*64*2)

typedef __attribute__((ext_vector_type(8))) short bf16x8;  // 8 bf16 (4 VGPRs)
typedef __attribute__((ext_vector_type(4))) float f32x4;
typedef unsigned int u32;
typedef const __attribute__((address_space(1))) u32* gas_u32p;
typedef __attribute__((address_space(3))) u32* las_u32p;

__device__ __forceinline__ short f2bf(float f) {
    union { float f; unsigned u; } v; v.f = f;
    unsigned r = v.u + 0x7fffu + ((v.u >> 16) & 1u);   // RNE, finite inputs only
    return (short)(r >> 16);
}

// ---------- kernel 1: scatter max pid into dense grid ----------
__global__ __launch_bounds__(256) void k_scatter(const int* __restrict__ coords,
                                                 int* __restrict__ grid) {
    int p = blockIdx.x * 256 + threadIdx.x;
    if (p >= BN_TOT) return;
    int b = p / NPTS;
    int x = coords[p*3+0], y = coords[p*3+1], z = coords[p*3+2];
    atomicMax(&grid[((b*GS + x)*GS + y)*GS + z], p);
}

// ---------- kernel 2: weight -> bf16 MFMA B-fragments ----------
// wfrag element t = ((((k*2+c)*4 + tt)*64 + lane)*8 + i)
//   holds W[k][ c*32 + (lane>>4)*8 + i ][ tt*16 + (lane&15) ]
__global__ __launch_bounds__(256) void k_prefrag(const float* __restrict__ w,
                                                 short* __restrict__ wfrag) {
    int t = blockIdx.x * 256 + threadIdx.x;
    if (t >= 27*2*4*64*8) return;
    int i    = t & 7;
    int lane = (t >> 3) & 63;
    int tt   = (t >> 9) & 3;
    int c    = (t >> 11) & 1;
    int k    = t >> 12;
    int kk = c*32 + (lane >> 4)*8 + i;
    int co = tt*16 + (lane & 15);
    wfrag[t] = f2bf(w[(k*64 + kk)*64 + co]);
}

// ---------- kernel 3: feats f32 -> bf16 rows ----------
__global__ __launch_bounds__(256) void k_tobf16(const float* __restrict__ f,
                                                ushort* __restrict__ o) {
    int i = blockIdx.x*256 + threadIdx.x;    // 2,400,000 threads x 8 elems
    if (i >= BN_TOT*8) return;
    const float4* s = (const float4*)(f + (size_t)i*8);
    float4 x = s[0], y = s[1];
    ushort4 lo = { (ushort)f2bf(x.x),(ushort)f2bf(x.y),(ushort)f2bf(x.z),(ushort)f2bf(x.w) };
    ushort4 hi = { (ushort)f2bf(y.x),(ushort)f2bf(y.y),(ushort)f2bf(y.z),(ushort)f2bf(y.w) };
    ushort4* d = (ushort4*)(o + (size_t)i*8);
    d[0] = lo; d[1] = hi;
}

// ---------- kernel 4: gathered MFMA conv, dense-27, LDS-staged B ----------
// 8 waves/block; wave = 32 points x 64 cout (2 row-tiles share B-frags).
// W[k] (8KB bf16 frags) double-buffered in LDS via global_load_lds;
// raw s_barrier + counted vmcnt(3): exactly 7 unconditional vmem/iter
// [a00,a01,a10,a11, idn0,idn1, stage(k+1)] + stage(k) outstanding from
// the previous iter -> vmcnt(3) drains stage(k)+A, keeps stage(k+1) flying.
__global__ __launch_bounds__(512, 4) void k_conv(
    const ushort* __restrict__ fb16,
    const int* __restrict__ coords,
    const int* __restrict__ grid,
    const ushort* __restrict__ wfrag,
    float* __restrict__ out,
    float* __restrict__ gstats)
{
    __shared__ __align__(16) ushort bufs[2][4096];   // 2 x 8KB
    __shared__ float bsum[64], bsq[64];

    const int tid  = threadIdx.x;
    const int lane = tid & 63;
    const int wv   = tid >> 6;
    const int r    = lane & 15;
    const int seg  = lane >> 4;
    const int p0   = blockIdx.x * 256 + wv * 32;
    const int pr0  = p0 + r;
    const int pr1  = pr0 + 16;

    int cx0=-9, cy0=-9, cz0=-9, cx1=-9, cy1=-9, cz1=-9;
    int gb0=0, gb1=0;
    if (pr0 < BN_TOT) { cx0=coords[pr0*3+0]; cy0=coords[pr0*3+1]; cz0=coords[pr0*3+2];
                        gb0 = (pr0 >= NPTS) ? GS3 : 0; }
    if (pr1 < BN_TOT) { cx1=coords[pr1*3+0]; cy1=coords[pr1*3+1]; cz1=coords[pr1*3+2];
                        gb1 = (pr1 >= NPTS) ? GS3 : 0; }

    // clamped, UNCONDITIONAL grid load (keeps per-wave vmcnt deterministic)
    auto lk = [&](int gb, int cx, int cy, int cz, int kk) -> int {
        int dx = kk/9 - 1, dy = (kk/3)%3 - 1, dz = kk%3 - 1;
        int nx = cx+dx, ny = cy+dy, nz = cz+dz;
        int ok = (int)(((unsigned)nx < (unsigned)GS) & ((unsigned)ny < (unsigned)GS) &
                       ((unsigned)nz < (unsigned)GS));
        int ax = nx & 127, ay = ny & 127, az = nz & 127;
        int id = grid[gb + (ax<<14) + (ay<<7) + az];
        return ok ? id : -1;
    };

    auto stage = [&](int kk, int bsel) {
        const u32* g = (const u32*)(wfrag + (size_t)kk*4096 + tid*8);
        u32* l = (u32*)(&bufs[bsel][wv*512]);          // wave-uniform base; HW adds lane*16
        __builtin_amdgcn_global_load_lds((gas_u32p)g, (las_u32p)l, 16, 0, 0);
    };

    const bf16x8 zz = {0,0,0,0,0,0,0,0};
    f32x4 c00={0,0,0,0}, c01={0,0,0,0}, c02={0,0,0,0}, c03={0,0,0,0};
    f32x4 c10={0,0,0,0}, c11={0,0,0,0}, c12={0,0,0,0}, c13={0,0,0,0};

    stage(0, 0);
    int id0 = lk(gb0,cx0,cy0,cz0, 0);
    int id1 = lk(gb1,cx1,cy1,cz1, 0);

    for (int k = 0; k < 27; ++k) {
        // A loads for current k (unconditional, clamped ids)
        const ushort* a0p = fb16 + (size_t)(id0 < 0 ? 0 : id0)*64;
        const ushort* a1p = fb16 + (size_t)(id1 < 0 ? 0 : id1)*64;
        bf16x8 a00 = *(const bf16x8*)(a0p + seg*8);
        bf16x8 a01 = *(const bf16x8*)(a0p + 32 + seg*8);
        bf16x8 a10 = *(const bf16x8*)(a1p + seg*8);
        bf16x8 a11 = *(const bf16x8*)(a1p + 32 + seg*8);
        // id prefetch for k+1 (dummy kn=0 at k=26 keeps counts uniform)
        int kn = (k == 26) ? 0 : k+1;
        int idn0 = lk(gb0,cx0,cy0,cz0, kn);
        int idn1 = lk(gb1,cx1,cy1,cz1, kn);
        // stage k+1 into the other buffer (dummy at k=26, never read)
        stage(kn, (k+1)&1);
        // zero invalid rows (ref's zero-row semantics)
        if (id0 < 0) { a00 = zz; a01 = zz; }
        if (id1 < 0) { a10 = zz; a11 = zz; }

        asm volatile("s_waitcnt vmcnt(3)" ::: "memory");  // drain stage(k)+A; keep stage(k+1)
        __builtin_amdgcn_s_barrier();
        __builtin_amdgcn_sched_barrier(0);

        const bf16x8* bb = (const bf16x8*)bufs[k&1];
        bf16x8 b00 = bb[0*64+lane], b01 = bb[1*64+lane],
               b02 = bb[2*64+lane], b03 = bb[3*64+lane],
               b10 = bb[4*64+lane], b11 = bb[5*64+lane],
               b12 = bb[6*64+lane], b13 = bb[7*64+lane];

        c00 = __builtin_amdgcn_mfma_f32_16x16x32_bf16(a00, b00, c00, 0,0,0);
        c01 = __builtin_amdgcn_mfma_f32_16x16x32_bf16(a00, b01, c01, 0,0,0);
        c02 = __builtin_amdgcn_mfma_f32_16x16x32_bf16(a00, b02, c02, 0,0,0);
        c03 = __builtin_amdgcn_mfma_f32_16x16x32_bf16(a00, b03, c03, 0,0,0);
        c00 = __builtin_amdgcn_mfma_f32_16x16x32_bf16(a01, b10, c00, 0,0,0);
        c01 = __builtin_amdgcn_mfma_f32_16x16x32_bf16(a01, b11, c01, 0,0,0);
        c02 = __builtin_amdgcn_mfma_f32_16x16x32_bf16(a01, b12, c02, 0,0,0);
        c03 = __builtin_amdgcn_mfma_f32_16x16x32_bf16(a01, b13, c03, 0,0,0);
        c10 = __builtin_amdgcn_mfma_f32_16x16x32_bf16(a10, b00, c10, 0,0,0);
        c11 = __builtin_amdgcn_mfma_f32_16x16x32_bf16(a10, b01, c11, 0,0,0);
        c12 = __builtin_amdgcn_mfma_f32_16x16x32_bf16(a10, b02, c12, 0,0,0);
        c13 = __builtin_amdgcn_mfma_f32_16x16x32_bf16(a10, b03, c13, 0,0,0);
        c10 = __builtin_amdgcn_mfma_f32_16x16x32_bf16(a11, b10, c10, 0,0,0);
        c11 = __builtin_amdgcn_mfma_f32_16x16x32_bf16(a11, b11, c11, 0,0,0);
        c12 = __builtin_amdgcn_mfma_f32_16x16x32_bf16(a11, b12, c12, 0,0,0);
        c13 = __builtin_amdgcn_mfma_f32_16x16x32_bf16(a11, b13, c13, 0,0,0);

        __builtin_amdgcn_sched_barrier(0);
        __builtin_amdgcn_s_barrier();      // everyone done reading buf[k&1]
        id0 = idn0; id1 = idn1;
    }

    // ---- epilogue: stores (C/D: col=lane&15, row=(lane>>4)*4+j, verified) ----
    {
        const int orow = seg*4;
        float* ob = out + (size_t)p0*64;
        #pragma unroll
        for (int j = 0; j < 4; ++j) {
            int row0 = orow + j;
            if (p0 + row0 < BN_TOT) {
                ob[row0*64 +  0 + r] = c00[j];
                ob[row0*64 + 16 + r] = c01[j];
                ob[row0*64 + 32 + r] = c02[j];
                ob[row0*64 + 48 + r] = c03[j];
            }
            int row1 = 16 + orow + j;
            if (p0 + row1 < BN_TOT) {
                ob[row1*64 +  0 + r] = c10[j];
                ob[row1*64 + 16 + r] = c11[j];
                ob[row1*64 + 32 + r] = c12[j];
                ob[row1*64 + 48 + r] = c13[j];
            }
        }
    }
    // ---- fused stats: per-channel sum / sumsq (pad rows contribute 0) ----
    if (tid < 64) { bsum[tid] = 0.f; bsq[tid] = 0.f; }
    __syncthreads();
    float s0=0,s1=0,s2=0,s3=0,q0=0,q1=0,q2=0,q3=0;
    #pragma unroll
    for (int j = 0; j < 4; ++j) {
        s0 += c00[j] + c10[j];  q0 += c00[j]*c00[j] + c10[j]*c10[j];
        s1 += c01[j] + c11[j];  q1 += c01[j]*c01[j] + c11[j]*c11[j];
        s2 += c02[j] + c12[j];  q2 += c02[j]*c02[j] + c12[j]*c12[j];
        s3 += c03[j] + c13[j];  q3 += c03[j]*c03[j] + c13[j]*c13[j];
    }
    atomicAdd(&bsum[ 0 + r], s0);  atomicAdd(&bsq[ 0 + r], q0);
    atomicAdd(&bsum[16 + r], s1);  atomicAdd(&bsq[16 + r], q1);
    atomicAdd(&bsum[32 + r], s2);  atomicAdd(&bsq[32 + r], q2);
    atomicAdd(&bsum[48 + r], s3);  atomicAdd(&bsq[48 + r], q3);
    __syncthreads();
    if (tid < 64) { atomicAdd(&gstats[tid], bsum[tid]); atomicAdd(&gstats[64+tid], bsq[tid]); }
}

// ---------- kernel 5: normalize + affine + ReLU, in place ----------
__global__ __launch_bounds__(256) void k_norm(float* __restrict__ out,
                                              const float* __restrict__ stats,
                                              const float* __restrict__ gamma,
                                              const float* __restrict__ beta) {
    int i = blockIdx.x*256 + threadIdx.x;
    const int n4 = BN_TOT*16;
    if (i >= n4) return;
    float4 v = ((const float4*)out)[i];
    int ch = (i & 15) * 4;
    float o[4] = {v.x, v.y, v.z, v.w};
    float rp[4];
    #pragma unroll
    for (int j = 0; j < 4; ++j) {
        int c = ch + j;
        float mean = stats[c] * (1.f/BN_TOT);
        float var  = stats[64+c] * (1.f/BN_TOT) - mean*mean;
        float y = (o[j] - mean) * rsqrtf(var + EPS) * gamma[c] + beta[c];
        rp[j] = fmaxf(y, 0.f);
    }
    float4 rv; rv.x = rp[0]; rv.y = rp[1]; rv.z = rp[2]; rv.w = rp[3];
    ((float4*)out)[i] = rv;
}

extern "C" void kernel_launch(void* const* d_in, const int* in_sizes, int n_in,
                              void* d_out, int out_size, void* d_ws, size_t ws_size,
                              hipStream_t stream) {
    const float* feats  = (const float*)d_in[0];
    const int*   coords = (const int*)d_in[1];
    const float* weight = (const float*)d_in[2];
    const float* gamma  = (const float*)d_in[3];
    const float* beta   = (const float*)d_in[4];
    float* out = (float*)d_out;

    char*   ws    = (char*)d_ws;
    int*    grid  = (int*)(ws + OFF_GRID);
    short*  wfrag = (short*)(ws + OFF_WFRAG);
    float*  stats = (float*)(ws + OFF_STATS);
    ushort* fb16  = (ushort*)(ws + OFF_FB16);

    hipMemsetAsync(grid, 0xFF, SZ_GRID, stream);           // all cells = -1
    hipMemsetAsync(stats, 0, 512, stream);

    k_scatter<<<(BN_TOT + 255)/256, 256, 0, stream>>>(coords, grid);
    k_prefrag<<<(27*2*4*64*8)/256, 256, 0, stream>>>(weight, (short*)wfrag);
    k_tobf16<<<(BN_TOT*8)/256, 256, 0, stream>>>(feats, fb16);
    k_conv<<<CONV_BLOCKS, 512, 0, stream>>>(fb16, coords, grid,
                                            (const ushort*)wfrag, out, stats);
    k_norm<<<(BN_TOT*16 + 255)/256, 256, 0, stream>>>(out, stats, gamma, beta);
}